// Round 10
// baseline (609.900 us; speedup 1.0000x reference)
//
#include <hip/hip_runtime.h>
#include <hip/hip_bf16.h>
#include <hip/hip_fp16.h>

// B=2 H=16 S=2048 DK=128, fp32 in/out. out = [context (B,H,S,DK) | attn (B,H,S,S)]
// R10: wave-local BARRIER-FREE design. prep -> fp16 K,V in d_ws (32MB).
// Each wave owns 16 q-rows + private 8KB LDS (K 4KB + V 4KB, single-buffered).
// Swapped QK (mfma(K,Q) -> S^T) puts P directly in PV's A-frag layout: no P
// LDS round-trip, no cross-lane ops, no s_barrier anywhere in the loops.
constexpr int Bc = 2, Hc = 16, Sc = 2048, Dc = 128;
constexpr int KT = 16;          // k-cols per tile
constexpr int NTt = Sc / KT;    // 128 tiles
constexpr size_t SK = (size_t)Sc * Dc;
constexpr float SCALE = 0.08838834764831844f;  // 1/sqrt(128)

typedef _Float16 half8 __attribute__((ext_vector_type(8)));
typedef _Float16 half4v __attribute__((ext_vector_type(4)));
typedef float float4v __attribute__((ext_vector_type(4)));

#define SB0() __builtin_amdgcn_sched_barrier(0)
#define LGKM0() { asm volatile("s_waitcnt lgkmcnt(0)" ::: "memory"); SB0(); }
#define VMCNT(N) { asm volatile("s_waitcnt vmcnt(" #N ")" ::: "memory"); SB0(); }
#define GLL16(G, L) __builtin_amdgcn_global_load_lds( \
    (const __attribute__((address_space(1))) void*)(G), \
    (__attribute__((address_space(3))) void*)(L), 16, 0, 0)

// ---------------- prep: fp32 -> fp16 copies of K and V ----------------
__global__ __launch_bounds__(256, 4)
void prep_kernel(const float* __restrict__ K, const float* __restrict__ V,
                 _Float16* __restrict__ Kh, _Float16* __restrict__ Vh)
{
    const int nb = gridDim.x >> 1;
    const bool isV = blockIdx.x >= nb;
    const float* src = isV ? V : K;
    _Float16* dst = isV ? Vh : Kh;
    const size_t base = ((size_t)(isV ? blockIdx.x - nb : blockIdx.x) * 256 + threadIdx.x) * 32;
    #pragma unroll
    for (int c = 0; c < 4; ++c) {
        float4v f0 = *(const float4v*)&src[base + c * 8];
        float4v f1 = *(const float4v*)&src[base + c * 8 + 4];
        half8 h8;
        #pragma unroll
        for (int i = 0; i < 4; ++i) { h8[i] = (_Float16)f0[i]; h8[4 + i] = (_Float16)f1[i]; }
        *(half8*)&dst[base + c * 8] = h8;
    }
}

// ---------------- main: wave-local barrier-free fused attention ----------------
__global__ __launch_bounds__(256, 2)
void sdpa_kernel(const float* __restrict__ Q, const _Float16* __restrict__ Kg,
                 const _Float16* __restrict__ Vg, const float* __restrict__ M,
                 float* __restrict__ outC, float* __restrict__ outA)
{
    __shared__ __align__(16) _Float16 Kl[4][KT * Dc];  // 4 waves x 4KB, XOR-swizzled rows
    __shared__ __align__(16) _Float16 Vl[4][KT * Dc];  // 4 waves x 4KB, tr-subtiled

    int bid = blockIdx.x;
    bid = (bid & 7) * 128 + (bid >> 3);   // XCD swizzle (1024 % 8 == 0)
    const int head = bid >> 5;
    const int q0   = (bid & 31) * 64;

    const int tid  = threadIdx.x;
    const int wv   = tid >> 6;
    const int lane = tid & 63;
    const int g    = lane >> 4;
    const int c16  = lane & 15;
    const int qrow0 = q0 + wv * 16;

    const float*    Qh  = Q  + (size_t)head * SK;
    const _Float16* Khh = Kg + (size_t)head * SK;
    const _Float16* Vhh = Vg + (size_t)head * SK;
    const float*    Mh  = M  + (size_t)head * Sc * Sc;
    float* Ch = outC + (size_t)head * SK;
    float* Ah = outA + (size_t)head * Sc * Sc;

    // ---- Q B-fragments (fp16): lane holds Q[q=c16][d = c*32 + g*8 + j] ----
    half8 aq[4];
    {
        const float* qp = Qh + (size_t)(qrow0 + c16) * Dc + g * 8;
        #pragma unroll
        for (int c = 0; c < 4; ++c) {
            float4v f0 = *(const float4v*)(qp + c * 32);
            float4v f1 = *(const float4v*)(qp + c * 32 + 4);
            half8 h;
            #pragma unroll
            for (int j = 0; j < 4; ++j) { h[j] = (_Float16)f0[j]; h[4 + j] = (_Float16)f1[j]; }
            aq[c] = h;
        }
    }

    // ---- per-lane pre-swizzled GLL source offsets (halves, rel. to tile) ----
    // K LDS: row kr, granule layout [kr][dgran ^ (kr&7)]
    // V LDS: [dd=8][kq=4][klow=4][dc=16] subtiles for ds_read_b64_tr_b16
    int srcKo[4], srcVo[4];
    #pragma unroll
    for (int i = 0; i < 4; ++i) {
        const int G = i * 64 + lane;
        const int kr = G >> 4, gcol = G & 15;
        srcKo[i] = kr * Dc + ((gcol * 8) ^ ((kr & 7) * 8));
        const int dd = G >> 5, kq = (G >> 3) & 3, klow = (G >> 1) & 3, dh = (G & 1) * 8;
        srcVo[i] = (kq * 4 + klow) * Dc + dd * 16 + dh;
    }

    auto stageK = [&](int t) {
        const _Float16* src = Khh + (size_t)t * KT * Dc;
        #pragma unroll
        for (int i = 0; i < 4; ++i) GLL16(src + srcKo[i], &Kl[wv][i * 512]);
    };
    auto stageV = [&](int t) {
        const _Float16* src = Vhh + (size_t)t * KT * Dc;
        #pragma unroll
        for (int i = 0; i < 4; ++i) GLL16(src + srcVo[i], &Vl[wv][i * 512]);
    };

    const int swr = (c16 & 7) * 8;

    // ================= Pass A: row sums of exp(scores), K only =================
    float psum = 0.f;
    stageK(0);
    for (int t = 0; t < NTt; ++t) {
        VMCNT(0);                       // K(t) staged
        half8 ak[4];
        #pragma unroll
        for (int c = 0; c < 4; ++c)
            ak[c] = *(const half8*)&Kl[wv][c16 * Dc + ((c * 32 + g * 8) ^ swr)];
        LGKM0();                        // reads retired -> buffer free
        stageK((t + 1) & (NTt - 1));    // prefetch next tile
        SB0();
        float4v accS = {0, 0, 0, 0};
        #pragma unroll
        for (int c = 0; c < 4; ++c)
            accS = __builtin_amdgcn_mfma_f32_16x16x32_f16(ak[c], aq[c], accS, 0, 0, 0);
        #pragma unroll
        for (int r = 0; r < 4; ++r)
            psum += __expf(accS[r] * SCALE);
    }
    // reduce over the 4 g-lane groups (lane bits 4,5)
    psum += __shfl_xor(psum, 16, 64);
    psum += __shfl_xor(psum, 32, 64);
    const float invl = 1.0f / psum;

    // ================= Pass B =================
    float4v accC[8];
    #pragma unroll
    for (int d = 0; d < 8; ++d) accC[d] = (float4v){0, 0, 0, 0};

    const unsigned int vbase = (unsigned int)(uintptr_t)(&Vl[wv][0]);
    const unsigned int lane8 = lane * 8;
    float4v m0;
    const float* mrow = Mh + (size_t)(qrow0 + c16) * Sc + g * 4;
    float* arow = Ah + (size_t)(qrow0 + c16) * Sc + g * 4;

    // prologue: tile 0 (K GLLs partly duplicate pass A's dangling wrap — benign)
    stageK(0); stageV(0);
    m0 = *(const float4v*)mrow;
    VMCNT(1);                           // K0,V0 landed (M0 may be in flight)

    for (int t = 0; t < NTt; ++t) {
        VMCNT(2);                       // G(t) done; leaves [store(t-1), M(t)]
        // V(t) B-frags: one hw-transpose read per d-chunk
        half4v vB[8];
        #pragma unroll
        for (int dd = 0; dd < 8; ++dd) {
            unsigned int a_ = vbase + dd * 512 + lane8;
            asm volatile("ds_read_b64_tr_b16 %0, %1" : "=v"(vB[dd]) : "v"(a_));
        }
        half8 ak[4];
        #pragma unroll
        for (int c = 0; c < 4; ++c)
            ak[c] = *(const half8*)&Kl[wv][c16 * Dc + ((c * 32 + g * 8) ^ swr)];
        LGKM0();                        // all LDS reads retired -> buffers free
        const int nt = (t + 1) & (NTt - 1);
        stageK(nt); stageV(nt);         // 8 GLL for tile t+1
        SB0();
        // swapped QK: accS[r] = S[q=c16][kc = t*16 + g*4 + r]
        float4v accS = {0, 0, 0, 0};
        #pragma unroll
        for (int c = 0; c < 4; ++c)
            accS = __builtin_amdgcn_mfma_f32_16x16x32_f16(ak[c], aq[c], accS, 0, 0, 0);
        VMCNT(8);                       // M(t) ready ([store(t-1),M(t),G(t+1)x8])
        float p[4];
        #pragma unroll
        for (int r = 0; r < 4; ++r)
            p[r] = __expf(accS[r] * SCALE) * invl;
        // attn store (float4, row c16, cols t*16 + g*4 ..+3)
        *(float4v*)(arow + (size_t)t * KT) = (float4v){p[0], p[1], p[2], p[3]};
        // blend with M -> PV A-frag (already in A layout, no transpose!)
        half4v ap;
        #pragma unroll
        for (int r = 0; r < 4; ++r)
            ap[r] = (_Float16)(0.7f * p[r] + 0.3f * m0[r]);
        m0 = *(const float4v*)(mrow + (size_t)((t + 1) & (NTt - 1)) * KT);
        // PV: 8 independent 16x16x16 MFMAs
        #pragma unroll
        for (int dd = 0; dd < 8; ++dd)
            accC[dd] = __builtin_amdgcn_mfma_f32_16x16x16f16(ap, vB[dd], accC[dd], 0, 0, 0);
    }

    // ================= epilogue: context =================
    #pragma unroll
    for (int dd = 0; dd < 8; ++dd)
        #pragma unroll
        for (int r = 0; r < 4; ++r)
            Ch[(size_t)(qrow0 + g * 4 + r) * Dc + dd * 16 + c16] = accC[dd][r];
}

extern "C" void kernel_launch(void* const* d_in, const int* in_sizes, int n_in,
                              void* d_out, int out_size, void* d_ws, size_t ws_size,
                              hipStream_t stream) {
    const float* Q = (const float*)d_in[0];
    const float* K = (const float*)d_in[1];
    const float* V = (const float*)d_in[2];
    const float* M = (const float*)d_in[4];   // d_in[3] = attn_mask (unused)
    float* outC = (float*)d_out;
    float* outA = outC + (size_t)Bc * Hc * SK;

    _Float16* Kh = (_Float16*)d_ws;            // 16MB
    _Float16* Vh = Kh + (size_t)Bc * Hc * SK;  // +16MB

    prep_kernel<<<dim3(2048), dim3(256), 0, stream>>>(K, V, Kh, Vh);
    sdpa_kernel<<<dim3(1024), dim3(256), 0, stream>>>(Q, Kh, Vh, M, outC, outA);
}

// Round 11
// 570.580 us; speedup vs baseline: 1.0689x; 1.0689x over previous
//
#include <hip/hip_runtime.h>
#include <hip/hip_bf16.h>
#include <hip/hip_fp16.h>

// B=2 H=16 S=2048 DK=128, fp32 in/out. out = [context (B,H,S,DK) | attn (B,H,S,S)]
// R11: 4-wave shared staging (L2-safe), swapped-operand QK (S^T -> P lands in
// PV 16x16x16 A-frag layout: NO P LDS round-trip), LDS=32KB -> 4-5 blocks/CU.
// GLL-direct staging + counted vmcnt (R9-proven), M 2-deep named prefetch.
constexpr int Bc = 2, Hc = 16, Sc = 2048, Dc = 128;
constexpr int KT = 32;          // k-cols per tile
constexpr int NT = Sc / KT;     // 64
constexpr size_t SK = (size_t)Sc * Dc;
constexpr float SCALE = 0.08838834764831844f;  // 1/sqrt(128)

typedef _Float16 half8 __attribute__((ext_vector_type(8)));
typedef _Float16 half4v __attribute__((ext_vector_type(4)));
typedef float float4v __attribute__((ext_vector_type(4)));

#define SB0() __builtin_amdgcn_sched_barrier(0)
#define SBAR() { SB0(); __builtin_amdgcn_s_barrier(); SB0(); }
#define LGKM0() { asm volatile("s_waitcnt lgkmcnt(0)" ::: "memory"); SB0(); }
#define LGKMC(N) { asm volatile("s_waitcnt lgkmcnt(" #N ")" ::: "memory"); SB0(); }
#define VMCNT(N) { asm volatile("s_waitcnt vmcnt(" #N ")" ::: "memory"); SB0(); }
#define GLL16(G, L) __builtin_amdgcn_global_load_lds( \
    (const __attribute__((address_space(1))) void*)(G), \
    (__attribute__((address_space(3))) void*)(L), 16, 0, 0)

// ---------------- prep: fp32 -> fp16 copies of K and V ----------------
__global__ __launch_bounds__(256, 4)
void prep_kernel(const float* __restrict__ K, const float* __restrict__ V,
                 _Float16* __restrict__ Kh, _Float16* __restrict__ Vh)
{
    const int nb = gridDim.x >> 1;
    const bool isV = blockIdx.x >= nb;
    const float* src = isV ? V : K;
    _Float16* dst = isV ? Vh : Kh;
    const size_t base = ((size_t)(isV ? blockIdx.x - nb : blockIdx.x) * 256 + threadIdx.x) * 32;
    #pragma unroll
    for (int c = 0; c < 4; ++c) {
        float4v f0 = *(const float4v*)&src[base + c * 8];
        float4v f1 = *(const float4v*)&src[base + c * 8 + 4];
        half8 h8;
        #pragma unroll
        for (int i = 0; i < 4; ++i) { h8[i] = (_Float16)f0[i]; h8[4 + i] = (_Float16)f1[i]; }
        *(half8*)&dst[base + c * 8] = h8;
    }
}

// ---------------- main ----------------
__global__ __launch_bounds__(256, 3)
void sdpa_kernel(const float* __restrict__ Q, const _Float16* __restrict__ Kg,
                 const _Float16* __restrict__ Vg, const float* __restrict__ M,
                 float* __restrict__ outC, float* __restrict__ outA)
{
    __shared__ __align__(16) _Float16 Kl[2][KT * Dc];  // 2x8KB, XOR-swizzled rows
    __shared__ __align__(16) _Float16 Vl[2][KT * Dc];  // 2x8KB, 2 halves x tr-subtiles

    int bid = blockIdx.x;
    bid = (bid & 7) * 128 + (bid >> 3);   // XCD swizzle (1024 % 8 == 0)
    const int head = bid >> 5;
    const int q0   = (bid & 31) * 64;

    const int tid  = threadIdx.x;
    const int wv   = tid >> 6;
    const int lane = tid & 63;
    const int g    = lane >> 4;
    const int c16  = lane & 15;
    const int qrow0 = q0 + wv * 16;

    const float*    Qh  = Q  + (size_t)head * SK;
    const _Float16* Khh = Kg + (size_t)head * SK;
    const _Float16* Vhh = Vg + (size_t)head * SK;
    const float*    Mh  = M  + (size_t)head * Sc * Sc;
    float* Ch = outC + (size_t)head * SK;
    float* Ah = outA + (size_t)head * Sc * Sc;

    // ---- Q fragment (B-operand of swapped QK): lane holds Q[q=c16][d=c*32+g*8+j]
    half8 aq[4];
    {
        const float* qp = Qh + (size_t)(qrow0 + c16) * Dc + g * 8;
        #pragma unroll
        for (int c = 0; c < 4; ++c) {
            float4v f0 = *(const float4v*)(qp + c * 32);
            float4v f1 = *(const float4v*)(qp + c * 32 + 4);
            half8 h;
            #pragma unroll
            for (int j = 0; j < 4; ++j) { h[j] = (_Float16)f0[j]; h[4 + j] = (_Float16)f1[j]; }
            aq[c] = h;
        }
    }

    // ---- GLL source offsets (halves, relative to tile start) ----
    // K: 512 granules, i in {0,1}: G = i*256+tid; row kr=G>>4; col swizzled
    int srcK[2];
    #pragma unroll
    for (int i = 0; i < 2; ++i) {
        const int G = i * 256 + tid;
        const int kr = G >> 4;
        srcK[i] = kr * Dc + (((G & 15) * 8) ^ ((kr & 7) * 8));
    }
    // V: per 16-k half h: G=tid: dd=G>>5, kq=(G>>3)&3, klow=(G>>1)&3, dh=(G&1)*8
    int srcV[2];
    {
        const int dd = tid >> 5, kq = (tid >> 3) & 3, klow = (tid >> 1) & 3, dh = (tid & 1) * 8;
        #pragma unroll
        for (int h = 0; h < 2; ++h)
            srcV[h] = (h * 16 + kq * 4 + klow) * Dc + dd * 16 + dh;
    }

    auto stageK = [&](int t, int buf) {
        const _Float16* src = Khh + (size_t)t * KT * Dc;
        #pragma unroll
        for (int i = 0; i < 2; ++i)
            GLL16(src + srcK[i], &Kl[buf][i * 2048 + wv * 512]);
    };
    auto stageV = [&](int t, int buf) {
        const _Float16* src = Vhh + (size_t)t * KT * Dc;
        #pragma unroll
        for (int h = 0; h < 2; ++h)
            GLL16(src + srcV[h], &Vl[buf][h * 2048 + wv * 512]);
    };

    const int swr = (c16 & 7) * 8;

    // swapped QK for tile in buf: accS[h][r] = S^T[k = h*16 + g*4 + r][q = c16]
#define QK(BUF, A0, A1) { \
    half8 ak0[4], ak1[4]; \
    _Pragma("unroll") \
    for (int c = 0; c < 4; ++c) { \
        ak0[c] = *(const half8*)&Kl[BUF][c16 * Dc + ((c * 32 + g * 8) ^ swr)]; \
        ak1[c] = *(const half8*)&Kl[BUF][(16 + c16) * Dc + ((c * 32 + g * 8) ^ swr)]; \
    } \
    LGKM0(); \
    stagePrefetch(); \
    _Pragma("unroll") \
    for (int c = 0; c < 4; ++c) \
        A0 = __builtin_amdgcn_mfma_f32_16x16x32_f16(ak0[c], aq[c], A0, 0, 0, 0); \
    _Pragma("unroll") \
    for (int c = 0; c < 4; ++c) \
        A1 = __builtin_amdgcn_mfma_f32_16x16x32_f16(ak1[c], aq[c], A1, 0, 0, 0); }

    // ================= Pass A: psum per q-row (K only) =================
    float psum = 0.f;
    {
        stageK(0, 0);
        VMCNT(0); SBAR();
        for (int t = 0; t < NT; ++t) {
            const int cur = t & 1;
            float4v a0 = {0,0,0,0}, a1 = {0,0,0,0};
            auto stagePrefetch = [&]() { stageK((t + 1) & (NT - 1), cur ^ 1); SB0(); };
            QK(cur, a0, a1)
            #pragma unroll
            for (int r = 0; r < 4; ++r)
                psum += __expf(a0[r] * SCALE) + __expf(a1[r] * SCALE);
            VMCNT(0); SBAR();
        }
    }
    psum += __shfl_xor(psum, 16, 64);
    psum += __shfl_xor(psum, 32, 64);
    const float invl = 1.0f / psum;

    // ================= Pass B =================
    float4v accC[8];
    #pragma unroll
    for (int d = 0; d < 8; ++d) accC[d] = (float4v){0, 0, 0, 0};

    const float* mrow = Mh + (size_t)(qrow0 + c16) * Sc + g * 4;
    float* arow = Ah + (size_t)(qrow0 + c16) * Sc + g * 4;
    float4v mA0, mA1, mB0, mB1;   // 2 named slots x (lo,hi)
#define LOADM(T, L, H) { const float* mp = mrow + (size_t)(T) * KT; \
    L = *(const float4v*)mp; H = *(const float4v*)(mp + 16); }

    stageK(0, 0); stageV(0, 0);
    LOADM(0, mA0, mA1)
    LOADM(1, mB0, mB1)
    VMCNT(4); SBAR();

    const unsigned int vbase0 = (unsigned int)(uintptr_t)(&Vl[0][0]);
    const unsigned int lane8 = lane * 8;

    half4v vS[4];                 // tr-read pipeline, 4 static slots
#define TRI(I) { unsigned int a_ = vb + ((I) >> 3) * 4096 + ((I) & 7) * 512 + lane8; \
    asm volatile("ds_read_b64_tr_b16 %0, %1" : "=&v"(vS[(I) & 3]) : "v"(a_)); }
#define PVS(I, N) { LGKMC(N); \
    accC[(I) & 7] = __builtin_amdgcn_mfma_f32_16x16x16f16( \
        ((I) < 8 ? ap0 : ap1), vS[(I) & 3], accC[(I) & 7], 0, 0, 0); }

#define BODY(T, M0, M1) { \
    const int cur = (T) & 1; \
    float4v a0 = {0,0,0,0}, a1 = {0,0,0,0}; \
    auto stagePrefetch = [&]() { \
        const int nt = ((T) + 1) & (NT - 1); \
        stageK(nt, cur ^ 1); stageV(nt, cur ^ 1); SB0(); }; \
    QK(cur, a0, a1) \
    float4v p0, p1; \
    _Pragma("unroll") \
    for (int r = 0; r < 4; ++r) { \
        p0[r] = __expf(a0[r] * SCALE) * invl; \
        p1[r] = __expf(a1[r] * SCALE) * invl; \
    } \
    *(float4v*)(arow + (size_t)(T) * KT)      = p0; \
    *(float4v*)(arow + (size_t)(T) * KT + 16) = p1; \
    half4v ap0, ap1; \
    _Pragma("unroll") \
    for (int r = 0; r < 4; ++r) { \
        ap0[r] = (_Float16)(0.7f * p0[r] + 0.3f * M0[r]); \
        ap1[r] = (_Float16)(0.7f * p1[r] + 0.3f * M1[r]); \
    } \
    LOADM((((T) + 2) & (NT - 1)), M0, M1) \
    const unsigned int vb = vbase0 + (unsigned int)(cur * (KT * Dc * 2)); \
    TRI(0) TRI(1) TRI(2) \
    TRI(3)  PVS(0, 3)  TRI(4)  PVS(1, 3)  TRI(5)  PVS(2, 3) \
    TRI(6)  PVS(3, 3)  TRI(7)  PVS(4, 3)  TRI(8)  PVS(5, 3) \
    TRI(9)  PVS(6, 3)  TRI(10) PVS(7, 3)  TRI(11) PVS(8, 3) \
    TRI(12) PVS(9, 3)  TRI(13) PVS(10, 3) TRI(14) PVS(11, 3) \
    TRI(15) PVS(12, 3) \
    PVS(13, 2) PVS(14, 1) PVS(15, 0) \
    VMCNT(4); SBAR(); }

    for (int t = 0; t < NT; t += 2) {
        BODY(t,     mA0, mA1)
        BODY(t + 1, mB0, mB1)
    }

    // ================= epilogue: context =================
    #pragma unroll
    for (int dd = 0; dd < 8; ++dd)
        #pragma unroll
        for (int r = 0; r < 4; ++r)
            Ch[(size_t)(qrow0 + g * 4 + r) * Dc + dd * 16 + c16] = accC[dd][r];
}

extern "C" void kernel_launch(void* const* d_in, const int* in_sizes, int n_in,
                              void* d_out, int out_size, void* d_ws, size_t ws_size,
                              hipStream_t stream) {
    const float* Q = (const float*)d_in[0];
    const float* K = (const float*)d_in[1];
    const float* V = (const float*)d_in[2];
    const float* M = (const float*)d_in[4];   // d_in[3] = attn_mask (unused)
    float* outC = (float*)d_out;
    float* outA = outC + (size_t)Bc * Hc * SK;

    _Float16* Kh = (_Float16*)d_ws;            // 16MB
    _Float16* Vh = Kh + (size_t)Bc * Hc * SK;  // +16MB

    prep_kernel<<<dim3(2048), dim3(256), 0, stream>>>(K, V, Kh, Vh);
    sdpa_kernel<<<dim3(1024), dim3(256), 0, stream>>>(Q, Kh, Vh, M, outC, outA);
}

// Round 12
// 503.280 us; speedup vs baseline: 1.2119x; 1.1337x over previous
//
#include <hip/hip_runtime.h>
#include <hip/hip_bf16.h>
#include <hip/hip_fp16.h>

// B=2 H=16 S=2048 DK=128, fp32 in/out. out = [context (B,H,S,DK) | attn (B,H,S,S)]
// R12: swapped-QK (no P LDS roundtrip) + 2 q-groups per wave (double ILP per
// chain step, shared K/V tiles) + GLL staging + counted vmcnt + 1 barrier/iter.
// Blocks: 128 threads (2 waves) x 64 q-rows; grid 1024 -> 4 blocks/CU.
constexpr int Bc = 2, Hc = 16, Sc = 2048, Dc = 128;
constexpr int KT = 32;
constexpr int NT = Sc / KT;     // 64
constexpr size_t SK = (size_t)Sc * Dc;
constexpr float SCALE = 0.08838834764831844f;  // 1/sqrt(128)

typedef _Float16 half8 __attribute__((ext_vector_type(8)));
typedef _Float16 half4v __attribute__((ext_vector_type(4)));
typedef float float4v __attribute__((ext_vector_type(4)));

#define SB0() __builtin_amdgcn_sched_barrier(0)
#define SBAR() { SB0(); __builtin_amdgcn_s_barrier(); SB0(); }
#define LGKM0() { asm volatile("s_waitcnt lgkmcnt(0)" ::: "memory"); SB0(); }
#define LGKMC(N) { asm volatile("s_waitcnt lgkmcnt(" #N ")" ::: "memory"); SB0(); }
#define VMCNT(N) { asm volatile("s_waitcnt vmcnt(" #N ")" ::: "memory"); SB0(); }
#define GLL16(G, L) __builtin_amdgcn_global_load_lds( \
    (const __attribute__((address_space(1))) void*)(G), \
    (__attribute__((address_space(3))) void*)(L), 16, 0, 0)

// ---------------- prep: fp32 -> fp16 copies of K and V ----------------
__global__ __launch_bounds__(256, 4)
void prep_kernel(const float* __restrict__ K, const float* __restrict__ V,
                 _Float16* __restrict__ Kh, _Float16* __restrict__ Vh)
{
    const int nb = gridDim.x >> 1;
    const bool isV = blockIdx.x >= nb;
    const float* src = isV ? V : K;
    _Float16* dst = isV ? Vh : Kh;
    const size_t base = ((size_t)(isV ? blockIdx.x - nb : blockIdx.x) * 256 + threadIdx.x) * 32;
    #pragma unroll
    for (int c = 0; c < 4; ++c) {
        float4v f0 = *(const float4v*)&src[base + c * 8];
        float4v f1 = *(const float4v*)&src[base + c * 8 + 4];
        half8 h8;
        #pragma unroll
        for (int i = 0; i < 4; ++i) { h8[i] = (_Float16)f0[i]; h8[4 + i] = (_Float16)f1[i]; }
        *(half8*)&dst[base + c * 8] = h8;
    }
}

// ---------------- main ----------------
__global__ __launch_bounds__(128, 2)
void sdpa_kernel(const float* __restrict__ Q, const _Float16* __restrict__ Kg,
                 const _Float16* __restrict__ Vg, const float* __restrict__ M,
                 float* __restrict__ outC, float* __restrict__ outA)
{
    __shared__ __align__(16) _Float16 Kl[2][KT * Dc];  // 2x8KB, XOR-swizzled rows
    __shared__ __align__(16) _Float16 Vl[2][KT * Dc];  // 2x8KB, 2 halves x tr-subtiles

    int bid = blockIdx.x;
    bid = (bid & 7) * 128 + (bid >> 3);   // XCD swizzle (1024 % 8 == 0)
    const int head = bid >> 5;
    const int q0   = (bid & 31) * 64;

    const int tid  = threadIdx.x;   // 0..127
    const int wv   = tid >> 6;      // 0..1
    const int lane = tid & 63;
    const int g    = lane >> 4;
    const int c16  = lane & 15;
    const int qr0  = q0 + wv * 16;  // q-group 0
    const int qr1  = qr0 + 32;      // q-group 1

    const float*    Qh  = Q  + (size_t)head * SK;
    const _Float16* Khh = Kg + (size_t)head * SK;
    const _Float16* Vhh = Vg + (size_t)head * SK;
    const float*    Mh  = M  + (size_t)head * Sc * Sc;
    float* Ch = outC + (size_t)head * SK;
    float* Ah = outA + (size_t)head * Sc * Sc;

    // ---- Q B-frags (swapped QK): lane holds Q[q=c16][d = c*32 + g*8 + j] ----
    half8 aq0[4], aq1[4];
    #pragma unroll
    for (int grp = 0; grp < 2; ++grp) {
        const float* qp = Qh + (size_t)((grp ? qr1 : qr0) + c16) * Dc + g * 8;
        #pragma unroll
        for (int c = 0; c < 4; ++c) {
            float4v f0 = *(const float4v*)(qp + c * 32);
            float4v f1 = *(const float4v*)(qp + c * 32 + 4);
            half8 h;
            #pragma unroll
            for (int j = 0; j < 4; ++j) { h[j] = (_Float16)f0[j]; h[4 + j] = (_Float16)f1[j]; }
            (grp ? aq1 : aq0)[c] = h;
        }
    }

    // ---- GLL source offsets (halves, relative to tile start) ----
    int srcK[4];
    #pragma unroll
    for (int i = 0; i < 4; ++i) {
        const int G = i * 128 + tid;
        const int kr = G >> 4;
        srcK[i] = kr * Dc + (((G & 15) * 8) ^ ((kr & 7) * 8));
    }
    int srcV[2][2];
    #pragma unroll
    for (int h = 0; h < 2; ++h)
        #pragma unroll
        for (int j = 0; j < 2; ++j) {
            const int Gv = j * 128 + tid;
            const int dd = Gv >> 5, kq = (Gv >> 3) & 3, kl = (Gv >> 1) & 3, dh = (Gv & 1) * 8;
            srcV[h][j] = (h * 16 + kq * 4 + kl) * Dc + dd * 16 + dh;
        }

    auto stageK = [&](int t, int buf) {
        const _Float16* s = Khh + (size_t)t * KT * Dc;
        #pragma unroll
        for (int i = 0; i < 4; ++i)
            GLL16(s + srcK[i], &Kl[buf][i * 1024 + wv * 512]);
    };
    auto stageV = [&](int t, int buf) {
        const _Float16* s = Vhh + (size_t)t * KT * Dc;
        #pragma unroll
        for (int h = 0; h < 2; ++h)
            #pragma unroll
            for (int j = 0; j < 2; ++j)
                GLL16(s + srcV[h][j], &Vl[buf][h * 2048 + j * 1024 + wv * 512]);
    };

    const int swr = (c16 & 7) * 8;

    // ================= Pass A: psum per q-row =================
    float ps0 = 0.f, ps1 = 0.f;
    stageK(0, 0);
    VMCNT(0); SBAR();
    for (int t = 0; t < NT; ++t) {
        const int cur = t & 1;
        stageK((t + 1) & (NT - 1), cur ^ 1); SB0();
        half8 ak0[4], ak1[4];
        #pragma unroll
        for (int c = 0; c < 4; ++c) {
            ak0[c] = *(const half8*)&Kl[cur][c16 * Dc + ((c * 32 + g * 8) ^ swr)];
            ak1[c] = *(const half8*)&Kl[cur][(16 + c16) * Dc + ((c * 32 + g * 8) ^ swr)];
        }
        LGKM0();
        float4v a00 = {0,0,0,0}, a01 = {0,0,0,0}, a10 = {0,0,0,0}, a11 = {0,0,0,0};
        #pragma unroll
        for (int c = 0; c < 4; ++c) {
            a00 = __builtin_amdgcn_mfma_f32_16x16x32_f16(ak0[c], aq0[c], a00, 0, 0, 0);
            a01 = __builtin_amdgcn_mfma_f32_16x16x32_f16(ak1[c], aq0[c], a01, 0, 0, 0);
            a10 = __builtin_amdgcn_mfma_f32_16x16x32_f16(ak0[c], aq1[c], a10, 0, 0, 0);
            a11 = __builtin_amdgcn_mfma_f32_16x16x32_f16(ak1[c], aq1[c], a11, 0, 0, 0);
        }
        #pragma unroll
        for (int r = 0; r < 4; ++r) {
            ps0 += __expf(a00[r] * SCALE) + __expf(a01[r] * SCALE);
            ps1 += __expf(a10[r] * SCALE) + __expf(a11[r] * SCALE);
        }
        VMCNT(0); SBAR();
    }
    ps0 += __shfl_xor(ps0, 16, 64); ps0 += __shfl_xor(ps0, 32, 64);
    ps1 += __shfl_xor(ps1, 16, 64); ps1 += __shfl_xor(ps1, 32, 64);
    const float il0 = 1.0f / ps0, il1 = 1.0f / ps1;

    // ================= Pass B =================
    float4v accC0[8], accC1[8];
    #pragma unroll
    for (int d = 0; d < 8; ++d) { accC0[d] = (float4v){0,0,0,0}; accC1[d] = (float4v){0,0,0,0}; }

    const float* mr0 = Mh + (size_t)(qr0 + c16) * Sc + g * 4;
    const float* mr1 = Mh + (size_t)(qr1 + c16) * Sc + g * 4;
    float* ar0 = Ah + (size_t)(qr0 + c16) * Sc + g * 4;
    float* ar1 = Ah + (size_t)(qr1 + c16) * Sc + g * 4;

    float4v mA00, mA01, mA10, mA11, mB00, mB01, mB10, mB11;
#define LOADM(T, M00, M01, M10, M11) { \
    const float* p0_ = mr0 + (size_t)(T) * KT; \
    const float* p1_ = mr1 + (size_t)(T) * KT; \
    M00 = *(const float4v*)p0_; M01 = *(const float4v*)(p0_ + 16); \
    M10 = *(const float4v*)p1_; M11 = *(const float4v*)(p1_ + 16); }

    // prologue: K(0) already in buf0 from pass A's wrap; stage V(0), M 2-deep
    stageV(0, 0); SB0();
    LOADM(0, mA00, mA01, mA10, mA11)
    LOADM(1, mB00, mB01, mB10, mB11)
    VMCNT(8); SBAR();   // drains the 4 V GLLs (8 M loads newer)

    const unsigned int vbase0 = (unsigned int)(uintptr_t)(&Vl[0][0]);
    const unsigned int lane8 = lane * 8;

    half4v vS0[4], vS1[4];   // tr-read slots (mod-4), h=0 / h=1
#define TRI(DD) { \
    unsigned int a0_ = vb + (DD) * 512 + lane8; \
    unsigned int a1_ = vb + 4096 + (DD) * 512 + lane8; \
    asm volatile("ds_read_b64_tr_b16 %0, %2\n\t" \
                 "ds_read_b64_tr_b16 %1, %3" \
                 : "=&v"(vS0[(DD) & 3]), "=&v"(vS1[(DD) & 3]) : "v"(a0_), "v"(a1_)); }
#define PVM(DD, N) { LGKMC(N); \
    accC0[DD] = __builtin_amdgcn_mfma_f32_16x16x16f16(ap00, vS0[(DD) & 3], accC0[DD], 0, 0, 0); \
    accC0[DD] = __builtin_amdgcn_mfma_f32_16x16x16f16(ap01, vS1[(DD) & 3], accC0[DD], 0, 0, 0); \
    accC1[DD] = __builtin_amdgcn_mfma_f32_16x16x16f16(ap10, vS0[(DD) & 3], accC1[DD], 0, 0, 0); \
    accC1[DD] = __builtin_amdgcn_mfma_f32_16x16x16f16(ap11, vS1[(DD) & 3], accC1[DD], 0, 0, 0); }

#define BODY(T, M00, M01, M10, M11) { \
    const int cur = (T) & 1; \
    const int nt = ((T) + 1) & (NT - 1); \
    stageK(nt, cur ^ 1); stageV(nt, cur ^ 1); SB0(); \
    half8 ak0[4], ak1[4]; \
    _Pragma("unroll") \
    for (int c = 0; c < 4; ++c) { \
        ak0[c] = *(const half8*)&Kl[cur][c16 * Dc + ((c * 32 + g * 8) ^ swr)]; \
        ak1[c] = *(const half8*)&Kl[cur][(16 + c16) * Dc + ((c * 32 + g * 8) ^ swr)]; \
    } \
    LGKM0(); \
    float4v a00 = {0,0,0,0}, a01 = {0,0,0,0}, a10 = {0,0,0,0}, a11 = {0,0,0,0}; \
    _Pragma("unroll") \
    for (int c = 0; c < 4; ++c) { \
        a00 = __builtin_amdgcn_mfma_f32_16x16x32_f16(ak0[c], aq0[c], a00, 0, 0, 0); \
        a01 = __builtin_amdgcn_mfma_f32_16x16x32_f16(ak1[c], aq0[c], a01, 0, 0, 0); \
        a10 = __builtin_amdgcn_mfma_f32_16x16x32_f16(ak0[c], aq1[c], a10, 0, 0, 0); \
        a11 = __builtin_amdgcn_mfma_f32_16x16x32_f16(ak1[c], aq1[c], a11, 0, 0, 0); \
    } \
    float4v p00, p01, p10, p11; \
    _Pragma("unroll") \
    for (int r = 0; r < 4; ++r) { \
        p00[r] = __expf(a00[r] * SCALE) * il0; \
        p01[r] = __expf(a01[r] * SCALE) * il0; \
        p10[r] = __expf(a10[r] * SCALE) * il1; \
        p11[r] = __expf(a11[r] * SCALE) * il1; \
    } \
    *(float4v*)(ar0 + (size_t)(T) * KT)      = p00; \
    *(float4v*)(ar0 + (size_t)(T) * KT + 16) = p01; \
    *(float4v*)(ar1 + (size_t)(T) * KT)      = p10; \
    *(float4v*)(ar1 + (size_t)(T) * KT + 16) = p11; \
    half4v ap00, ap01, ap10, ap11; \
    _Pragma("unroll") \
    for (int r = 0; r < 4; ++r) { \
        ap00[r] = (_Float16)(0.7f * p00[r] + 0.3f * M00[r]); \
        ap01[r] = (_Float16)(0.7f * p01[r] + 0.3f * M01[r]); \
        ap10[r] = (_Float16)(0.7f * p10[r] + 0.3f * M10[r]); \
        ap11[r] = (_Float16)(0.7f * p11[r] + 0.3f * M11[r]); \
    } \
    LOADM((((T) + 2) & (NT - 1)), M00, M01, M10, M11) \
    const unsigned int vb = vbase0 + (unsigned int)(cur * (KT * Dc * 2)); \
    TRI(0) TRI(1) TRI(2) \
    TRI(3) PVM(0, 6) \
    TRI(4) PVM(1, 6) \
    TRI(5) PVM(2, 6) \
    TRI(6) PVM(3, 6) \
    TRI(7) PVM(4, 6) \
    PVM(5, 4) PVM(6, 2) PVM(7, 0) \
    VMCNT(8); SBAR(); }

    for (int t = 0; t < NT; t += 2) {
        BODY(t,     mA00, mA01, mA10, mA11)
        BODY(t + 1, mB00, mB01, mB10, mB11)
    }

    // ================= epilogue: context =================
    #pragma unroll
    for (int dd = 0; dd < 8; ++dd)
        #pragma unroll
        for (int r = 0; r < 4; ++r) {
            Ch[(size_t)(qr0 + g * 4 + r) * Dc + dd * 16 + c16] = accC0[dd][r];
            Ch[(size_t)(qr1 + g * 4 + r) * Dc + dd * 16 + c16] = accC1[dd][r];
        }
}

extern "C" void kernel_launch(void* const* d_in, const int* in_sizes, int n_in,
                              void* d_out, int out_size, void* d_ws, size_t ws_size,
                              hipStream_t stream) {
    const float* Q = (const float*)d_in[0];
    const float* K = (const float*)d_in[1];
    const float* V = (const float*)d_in[2];
    const float* M = (const float*)d_in[4];   // d_in[3] = attn_mask (unused)
    float* outC = (float*)d_out;
    float* outA = outC + (size_t)Bc * Hc * SK;

    _Float16* Kh = (_Float16*)d_ws;            // 16MB
    _Float16* Vh = Kh + (size_t)Bc * Hc * SK;  // +16MB

    prep_kernel<<<dim3(2048), dim3(256), 0, stream>>>(K, V, Kh, Vh);
    sdpa_kernel<<<dim3(1024), dim3(128), 0, stream>>>(Q, Kh, Vh, M, outC, outA);
}